// Round 15
// baseline (424.515 us; speedup 1.0000x reference)
//
#include <hip/hip_runtime.h>
#include <hip/hip_bf16.h>

#define Bb 4
#define Tt 256
#define Uu 128
#define H1 512
#define H2 640
#define Dd 640
#define V1c 1025

typedef __bf16 bf16x8 __attribute__((ext_vector_type(8)));
typedef unsigned short ushort8 __attribute__((ext_vector_type(8)));
typedef unsigned short ushort4v __attribute__((ext_vector_type(4)));
typedef float floatx4 __attribute__((ext_vector_type(4)));

static __device__ __forceinline__ unsigned short f2bf(float x) {
    union { float f; unsigned u; } a; a.f = x;
    unsigned r = a.u + 0x7fffu + ((a.u >> 16) & 1u);
    return (unsigned short)(r >> 16);
}
static __device__ __forceinline__ float bf2f(unsigned short x) {
    union { unsigned u; float f; } a; a.u = ((unsigned)x) << 16; return a.f;
}

// ---------------- prep: fg linears (blocks 0..191) + Wb2 swizzle (192..351) ----------------
__global__ __launch_bounds__(640) void prep(const float* __restrict__ enc,
                                            const float* __restrict__ Wenc,
                                            const float* __restrict__ benc,
                                            float* __restrict__ f,
                                            const float* __restrict__ pred,
                                            const float* __restrict__ Wpred,
                                            const float* __restrict__ bpred,
                                            float* __restrict__ g,
                                            const float* __restrict__ Wout,
                                            unsigned short* __restrict__ Wb2,
                                            float* __restrict__ wtail) {
    __shared__ __align__(16) float sh[640 * 8];
    const int tid = threadIdx.x;

    if (blockIdx.x < 192) {
        const bool isF = blockIdx.x < 128;
        const float* in   = isF ? enc : pred;
        const float* W    = isF ? Wenc : Wpred;
        const float* bias = isF ? benc : bpred;
        float* out        = isF ? f : g;
        const int H    = isF ? H1 : H2;
        const int Tdim = isF ? Tt : Uu;
        const int blk  = isF ? (int)blockIdx.x : (int)blockIdx.x - 128;
        const int tBlocks = Tdim >> 3;
        const int b  = blk / tBlocks;
        const int t0 = (blk % tBlocks) << 3;
        const float* inB = in + (size_t)b * H * Tdim + t0;

        for (int h = tid; h < H; h += 640) {
            float4 v0 = *(const float4*)(inB + (size_t)h * Tdim);
            float4 v1 = *(const float4*)(inB + (size_t)h * Tdim + 4);
            *(float4*)(&sh[h * 8])     = v0;
            *(float4*)(&sh[h * 8 + 4]) = v1;
        }
        __syncthreads();

        const int d = tid;
        float acc[8];
        #pragma unroll
        for (int j = 0; j < 8; ++j) acc[j] = 0.f;
        #pragma unroll 4
        for (int h = 0; h < H; ++h) {
            float w = W[(size_t)h * Dd + d];
            float4 s0 = *(const float4*)(&sh[h * 8]);
            float4 s1 = *(const float4*)(&sh[h * 8 + 4]);
            acc[0] += s0.x * w; acc[1] += s0.y * w; acc[2] += s0.z * w; acc[3] += s0.w * w;
            acc[4] += s1.x * w; acc[5] += s1.y * w; acc[6] += s1.z * w; acc[7] += s1.w * w;
        }
        float bv = bias[d];
        float* o = out + ((size_t)b * Tdim + t0) * Dd + d;
        #pragma unroll
        for (int j = 0; j < 8; ++j) o[(size_t)j * Dd] = acc[j] + bv;
    } else {
        float (*tile)[129] = (float(*)[129])sh;    // 32 x 129 (padded)
        const int blk2 = blockIdx.x - 192;         // 0..159
        const int w = blk2 / 20;
        const int db = blk2 % 20;

        for (int idx = tid; idx < 4096; idx += 640) {
            int d_loc = idx >> 7;
            int v_loc = idx & 127;
            tile[d_loc][v_loc] = Wout[(size_t)(db * 32 + d_loc) * V1c + w * 128 + v_loc];
        }
        __syncthreads();

        if (tid < 512) {
            int gidx = tid;
            int nt  = gidx >> 6;
            int rem = gidx & 63;
            int l15 = rem >> 2;
            int lg  = rem & 3;
            int v_loc = nt * 16 + l15;
            ushort8 pk;
            #pragma unroll
            for (int j = 0; j < 8; ++j) pk[j] = f2bf(tile[lg * 8 + j][v_loc]);
            *(ushort8*)(Wb2 + (size_t)w * 81920 + db * 4096 + gidx * 8) = pk;
        }
        if (blk2 == 0 && tid < Dd) wtail[tid] = Wout[(size_t)tid * V1c + 1024];
    }
}

// ---------------- fused joint + log-softmax ----------------
// 2048 blocks x 512 thr (8 waves). Block: 64 rows x 1025 cols; wave tile 64x128.
// R15 = R12 exactly (full-panel stage, 20-step K-loop on Wb2 contiguous B,
// post-K tail dot, 4x16-row LDS-staged epilogue) with ONE change: epilogue
// drain uses PLAIN stores (barrier vmcnt-drain waits L2 ack, not HBM NT
// completion; writeback overlaps subsequent work).
__global__ __launch_bounds__(512, 2) void joint_main(const float* __restrict__ f,
                                                     const float* __restrict__ g,
                                                     const unsigned short* __restrict__ Wb2,
                                                     const float* __restrict__ wtail,
                                                     const float* __restrict__ b_out,
                                                     float* __restrict__ out) {
    __shared__ __align__(16) union UU {
        unsigned short hlds[2 * 64 * 328];   // 83,968 B (two half-panels, stride 328)
        float sOut[16 * 1025];               // 65,600 B (aliases dead hlds)
    } u;
    __shared__ float wtld[640];
    __shared__ float sPart[8 * 64];
    __shared__ float sRed[64];
    __shared__ float sTail[64];

    const int tid = threadIdx.x;
    const int l = tid & 63;
    const int w = tid >> 6;
    const int l15 = l & 15;
    const int lg = l >> 4;

    const int blk = blockIdx.x;
    const int uhalf = blk & 1;
    const int t = (blk >> 1) & 255;
    const int b = blk >> 9;
    const int u0 = uhalf * 64;
    const size_t fbase = ((size_t)b * Tt + t) * Dd;
    const size_t gbase = ((size_t)b * Uu + u0) * Dd;
    const size_t rowbase = (size_t)(b * Tt + t) * Uu + u0;

    // stage wtail (fp32) into LDS
    for (int i = tid; i < Dd; i += 512) wtld[i] = wtail[i];

    floatx4 acc[4][8];
    #pragma unroll
    for (int i = 0; i < 4; ++i)
        #pragma unroll
        for (int j = 0; j < 8; ++j) acc[i][j] = (floatx4){0.f, 0.f, 0.f, 0.f};

    const unsigned short* __restrict__ bbase = Wb2 + (size_t)w * 81920 + (l15 * 32 + lg * 8);
    float tailAcc = 0.f;
    const int srow = w * 8 + (l >> 3);
    const int ssub = l & 7;

    // ---- stage FULL h = relu(f+g) panel: 64 rows x 640 cols bf16 ----
    {
        const int row = tid >> 3;
        const float* frow = f + fbase;
        const float* grow = g + gbase + (size_t)row * Dd;
        #pragma unroll
        for (int j = 0; j < 20; ++j) {
            int c4 = (tid & 7) + 8 * j;        // float4 slot 0..159
            int d = c4 * 4;
            int half = (j >= 10) ? 1 : 0;
            int cloc = c4 - half * 80;
            float4 fv = *(const float4*)(frow + d);
            float4 gv = *(const float4*)(grow + d);
            float h0 = fv.x + gv.x; h0 = h0 > 0.f ? h0 : 0.f;
            float h1 = fv.y + gv.y; h1 = h1 > 0.f ? h1 : 0.f;
            float h2 = fv.z + gv.z; h2 = h2 > 0.f ? h2 : 0.f;
            float h3 = fv.w + gv.w; h3 = h3 > 0.f ? h3 : 0.f;
            ushort4v pk;
            pk.x = f2bf(h0); pk.y = f2bf(h1); pk.z = f2bf(h2); pk.w = f2bf(h3);
            *(ushort4v*)(&u.hlds[half * 20992 + row * 328 + cloc * 4]) = pk;
        }
    }
    __syncthreads();

    // ---- K loop: 20 steps of 32, B double-buffered in regs, no barriers ----
    {
        ushort8 Bbuf[2][8];
        #pragma unroll
        for (int nt = 0; nt < 8; ++nt)
            Bbuf[0][nt] = *(const ushort8*)(bbase + nt * 512);
        #pragma unroll
        for (int ksg = 0; ksg < 20; ++ksg) {
            if (ksg < 19) {
                #pragma unroll
                for (int nt = 0; nt < 8; ++nt)
                    Bbuf[(ksg + 1) & 1][nt] =
                        *(const ushort8*)(bbase + (ksg + 1) * 4096 + nt * 512);
            }
            const int bufo = (ksg >= 10) ? 20992 : 0;
            const int ks = (ksg >= 10) ? (ksg - 10) : ksg;
            bf16x8 afrag[4];
            #pragma unroll
            for (int mt = 0; mt < 4; ++mt) {
                ushort8 av = *(const ushort8*)(&u.hlds[bufo + (mt * 16 + l15) * 328 + ks * 32 + lg * 8]);
                afrag[mt] = __builtin_bit_cast(bf16x8, av);
            }
            #pragma unroll
            for (int nt = 0; nt < 8; ++nt) {
                bf16x8 bfrag = __builtin_bit_cast(bf16x8, Bbuf[ksg & 1][nt]);
                #pragma unroll
                for (int mt = 0; mt < 4; ++mt) {
                    acc[mt][nt] = __builtin_amdgcn_mfma_f32_16x16x32_bf16(
                        afrag[mt], bfrag, acc[mt][nt], 0, 0, 0);
                }
            }
        }
    }

    // ---- tail column: dot(h_row, wtail) from LDS ----
    #pragma unroll
    for (int j = 0; j < 20; ++j) {
        int c4 = ssub + 8 * j;                 // 0..159
        int half = (j >= 10) ? 1 : 0;
        int cloc = c4 - half * 80;
        ushort4v hv = *(const ushort4v*)(&u.hlds[half * 20992 + srow * 328 + cloc * 4]);
        float4 wv = *(const float4*)(&wtld[c4 * 4]);
        tailAcc += bf2f(hv.x) * wv.x + bf2f(hv.y) * wv.y +
                   bf2f(hv.z) * wv.z + bf2f(hv.w) * wv.w;
    }

    tailAcc += __shfl_xor(tailAcc, 1);
    tailAcc += __shfl_xor(tailAcc, 2);
    tailAcc += __shfl_xor(tailAcc, 4);
    if (ssub == 0) sTail[srow] = tailAcc + b_out[1024];

    // ---- + b_out ----
    #pragma unroll
    for (int nt = 0; nt < 8; ++nt) {
        float bo = b_out[w * 128 + nt * 16 + l15];
        #pragma unroll
        for (int mt = 0; mt < 4; ++mt)
            #pragma unroll
            for (int r = 0; r < 4; ++r) acc[mt][nt][r] += bo;
    }

    // ---- row max ----
    #pragma unroll
    for (int mt = 0; mt < 4; ++mt) {
        #pragma unroll
        for (int r = 0; r < 4; ++r) {
            float m = acc[mt][0][r];
            #pragma unroll
            for (int nt = 1; nt < 8; ++nt) m = fmaxf(m, acc[mt][nt][r]);
            #pragma unroll
            for (int msk = 1; msk < 16; msk <<= 1) m = fmaxf(m, __shfl_xor(m, msk));
            if (l15 == 0) sPart[w * 64 + mt * 16 + lg * 4 + r] = m;
        }
    }
    __syncthreads();
    if (tid < 64) {
        float m = sTail[tid];
        #pragma unroll
        for (int ww = 0; ww < 8; ++ww) m = fmaxf(m, sPart[ww * 64 + tid]);
        sRed[tid] = m;
    }
    __syncthreads();

    // ---- sum exp ----
    #pragma unroll
    for (int mt = 0; mt < 4; ++mt) {
        #pragma unroll
        for (int r = 0; r < 4; ++r) {
            int row = mt * 16 + lg * 4 + r;
            float mx = sRed[row];
            float sv = 0.f;
            #pragma unroll
            for (int nt = 0; nt < 8; ++nt) sv += __expf(acc[mt][nt][r] - mx);
            #pragma unroll
            for (int msk = 1; msk < 16; msk <<= 1) sv += __shfl_xor(sv, msk);
            if (l15 == 0) sPart[w * 64 + row] = sv;
        }
    }
    __syncthreads();
    if (tid < 64) {
        float mx = sRed[tid];
        float sv = __expf(sTail[tid] - mx);
        #pragma unroll
        for (int ww = 0; ww < 8; ++ww) sv += sPart[ww * 64 + tid];
        sRed[tid] = mx + logf(sv);  // lse
    }
    __syncthreads();   // sRed ready; hlds dead -> sOut aliasing OK

    // ---- write: 4 groups of 16 rows, LDS-staged, PLAIN float4 drain ----
    #pragma unroll
    for (int grp = 0; grp < 4; ++grp) {
        #pragma unroll
        for (int nt = 0; nt < 8; ++nt) {
            #pragma unroll
            for (int r = 0; r < 4; ++r) {
                u.sOut[(lg * 4 + r) * 1025 + w * 128 + nt * 16 + l15] =
                    acc[grp][nt][r] - sRed[grp * 16 + lg * 4 + r];
            }
        }
        if (tid < 16) u.sOut[tid * 1025 + 1024] = sTail[grp * 16 + tid] - sRed[grp * 16 + tid];
        __syncthreads();
        // 16*1025 = 16400 floats = 4100 float4
        float* outp = out + (rowbase + grp * 16) * (size_t)V1c;
        #pragma unroll
        for (int k = 0; k < 8; ++k) {
            int i4 = tid + 512 * k;
            *(floatx4*)(outp + 4 * i4) = *(const floatx4*)(&u.sOut[4 * i4]);
        }
        if (tid < 4) {
            int i4 = tid + 4096;
            *(floatx4*)(outp + 4 * i4) = *(const floatx4*)(&u.sOut[4 * i4]);
        }
        __syncthreads();
    }
}

extern "C" void kernel_launch(void* const* d_in, const int* in_sizes, int n_in,
                              void* d_out, int out_size, void* d_ws, size_t ws_size,
                              hipStream_t stream) {
    const float* enc   = (const float*)d_in[0];
    const float* pred  = (const float*)d_in[1];
    const float* Wenc  = (const float*)d_in[2];
    const float* benc  = (const float*)d_in[3];
    const float* Wpred = (const float*)d_in[4];
    const float* bpred = (const float*)d_in[5];
    const float* Wout  = (const float*)d_in[6];
    const float* bout  = (const float*)d_in[7];

    float* f = (float*)d_ws;                                     // 655360 f32
    float* g = f + (size_t)Bb * Tt * Dd;                         // 327680 f32
    unsigned short* Wb2 = (unsigned short*)(g + (size_t)Bb * Uu * Dd);  // 655360 u16
    float* wtail = (float*)(Wb2 + 8 * 81920);                    // 640 f32

    prep<<<352, 640, 0, stream>>>(enc, Wenc, benc, f, pred, Wpred, bpred, g,
                                  Wout, Wb2, wtail);
    joint_main<<<Bb * Tt * 2, 512, 0, stream>>>(f, g, Wb2, wtail, bout, (float*)d_out);
}

// Round 16
// 375.922 us; speedup vs baseline: 1.1293x; 1.1293x over previous
//
#include <hip/hip_runtime.h>
#include <hip/hip_bf16.h>

#define Bb 4
#define Tt 256
#define Uu 128
#define H1 512
#define H2 640
#define Dd 640
#define V1c 1025

typedef __bf16 bf16x8 __attribute__((ext_vector_type(8)));
typedef unsigned short ushort8 __attribute__((ext_vector_type(8)));
typedef unsigned short ushort4v __attribute__((ext_vector_type(4)));
typedef float floatx4 __attribute__((ext_vector_type(4)));
typedef float floatx16 __attribute__((ext_vector_type(16)));

static __device__ __forceinline__ unsigned short f2bf(float x) {
    union { float f; unsigned u; } a; a.f = x;
    unsigned r = a.u + 0x7fffu + ((a.u >> 16) & 1u);
    return (unsigned short)(r >> 16);
}
static __device__ __forceinline__ float bf2f(unsigned short x) {
    union { unsigned u; float f; } a; a.u = ((unsigned)x) << 16; return a.f;
}

// ---------------- prep: fg linears (blocks 0..191) + Wb3 swizzle (192..511) ----------------
// Wb3[cg][ks][ct][l31][lh][8] (ushort): 32x32x16 B-fragment order.
// offset = cg*81920 + ks*2048 + ct*512 + l31*16 + lh*8 + j
// source: v = cg*128 + ct*32 + l31 ; d = ks*16 + lh*8 + j   (ks 0..39)
__global__ __launch_bounds__(640) void prep(const float* __restrict__ enc,
                                            const float* __restrict__ Wenc,
                                            const float* __restrict__ benc,
                                            float* __restrict__ f,
                                            const float* __restrict__ pred,
                                            const float* __restrict__ Wpred,
                                            const float* __restrict__ bpred,
                                            float* __restrict__ g,
                                            const float* __restrict__ Wout,
                                            unsigned short* __restrict__ Wb3,
                                            float* __restrict__ wtail) {
    __shared__ __align__(16) float sh[640 * 8];
    const int tid = threadIdx.x;

    if (blockIdx.x < 192) {
        const bool isF = blockIdx.x < 128;
        const float* in   = isF ? enc : pred;
        const float* W    = isF ? Wenc : Wpred;
        const float* bias = isF ? benc : bpred;
        float* out        = isF ? f : g;
        const int H    = isF ? H1 : H2;
        const int Tdim = isF ? Tt : Uu;
        const int blk  = isF ? (int)blockIdx.x : (int)blockIdx.x - 128;
        const int tBlocks = Tdim >> 3;
        const int b  = blk / tBlocks;
        const int t0 = (blk % tBlocks) << 3;
        const float* inB = in + (size_t)b * H * Tdim + t0;

        for (int h = tid; h < H; h += 640) {
            float4 v0 = *(const float4*)(inB + (size_t)h * Tdim);
            float4 v1 = *(const float4*)(inB + (size_t)h * Tdim + 4);
            *(float4*)(&sh[h * 8])     = v0;
            *(float4*)(&sh[h * 8 + 4]) = v1;
        }
        __syncthreads();

        const int d = tid;
        float acc[8];
        #pragma unroll
        for (int j = 0; j < 8; ++j) acc[j] = 0.f;
        #pragma unroll 4
        for (int h = 0; h < H; ++h) {
            float w = W[(size_t)h * Dd + d];
            float4 s0 = *(const float4*)(&sh[h * 8]);
            float4 s1 = *(const float4*)(&sh[h * 8 + 4]);
            acc[0] += s0.x * w; acc[1] += s0.y * w; acc[2] += s0.z * w; acc[3] += s0.w * w;
            acc[4] += s1.x * w; acc[5] += s1.y * w; acc[6] += s1.z * w; acc[7] += s1.w * w;
        }
        float bv = bias[d];
        float* o = out + ((size_t)b * Tdim + t0) * Dd + d;
        #pragma unroll
        for (int j = 0; j < 8; ++j) o[(size_t)j * Dd] = acc[j] + bv;
    } else {
        // one block per (cg, ks): 16 d-rows x 128 v-cols
        float (*tile)[129] = (float(*)[129])sh;    // 16 x 129 (padded)
        const int blk2 = blockIdx.x - 192;         // 0..319
        const int cg = blk2 / 40;
        const int ks = blk2 % 40;

        if (tid < 512) {
            #pragma unroll
            for (int i = 0; i < 4; ++i) {
                int idx = tid + 512 * i;           // 0..2047
                int d_loc = idx >> 7;              // 0..15
                int v_loc = idx & 127;
                tile[d_loc][v_loc] = Wout[(size_t)(ks * 16 + d_loc) * V1c + cg * 128 + v_loc];
            }
        }
        __syncthreads();

        if (tid < 256) {
            int ct  = tid >> 6;
            int rem = tid & 63;
            int l31 = rem >> 1;
            int lh  = rem & 1;
            int v_loc = ct * 32 + l31;
            ushort8 pk;
            #pragma unroll
            for (int j = 0; j < 8; ++j) pk[j] = f2bf(tile[lh * 8 + j][v_loc]);
            *(ushort8*)(Wb3 + (size_t)cg * 81920 + ks * 2048 + tid * 8) = pk;
        }
        if (blk2 == 0 && tid < Dd) wtail[tid] = Wout[(size_t)tid * V1c + 1024];
    }
}

// ---------------- fused joint + log-softmax (32x32x16 MFMA, 16 waves) ----------------
// 2048 blocks x 1024 thr. Block: 64 rows x 1025 cols.
// Wave grid: 2 row-groups x 8 col-groups; wave tile 32x128 = 4 tiles of 32x32.
// acc = 4 x f32x16 = 64 AGPR -> ~115 regs/thread < 128 cap -> 4 waves/SIMD.
// B traffic unchanged vs R12 (1.31MB/block); B-loads contiguous 1KB (Wb3).
__global__ __launch_bounds__(1024) void joint_main(const float* __restrict__ f,
                                                   const float* __restrict__ g,
                                                   const unsigned short* __restrict__ Wb3,
                                                   const float* __restrict__ wtail,
                                                   const float* __restrict__ b_out,
                                                   float* __restrict__ out) {
    __shared__ __align__(16) union UU {
        unsigned short hlds[2 * 64 * 328];   // 83,968 B (two half-panels, stride 328)
        float sOut[16 * 1025];               // 65,600 B (aliases dead hlds)
    } u;
    __shared__ float wtld[640];
    __shared__ float sPart[8 * 64];
    __shared__ float sRed[64];
    __shared__ float sTail[64];

    const int tid = threadIdx.x;
    const int l = tid & 63;
    const int w = tid >> 6;       // wave 0..15
    const int rg = w >> 3;        // row group 0..1 (32 rows)
    const int cg = w & 7;         // col group 0..7 (128 cols)
    const int l31 = l & 31;
    const int lh = l >> 5;        // 0/1

    const int blk = blockIdx.x;
    const int uhalf = blk & 1;
    const int t = (blk >> 1) & 255;
    const int b = blk >> 9;
    const int u0 = uhalf * 64;
    const size_t fbase = ((size_t)b * Tt + t) * Dd;
    const size_t gbase = ((size_t)b * Uu + u0) * Dd;
    const size_t rowbase = (size_t)(b * Tt + t) * Uu + u0;

    if (tid < Dd) wtld[tid] = wtail[tid];

    floatx16 acc[4];
    #pragma unroll
    for (int ct = 0; ct < 4; ++ct)
        #pragma unroll
        for (int r = 0; r < 16; ++r) acc[ct][r] = 0.f;

    const unsigned short* __restrict__ bbase = Wb3 + (size_t)cg * 81920 + (l31 * 16 + lh * 8);
    float tailAcc = 0.f;
    const int srow = tid >> 4;    // 64 rows, 16 threads each
    const int ssub = tid & 15;

    // ---- stage FULL h = relu(f+g) panel: 64 rows x 640 cols bf16 ----
    {
        const int row = tid >> 4;
        const float* frow = f + fbase;
        const float* grow = g + gbase + (size_t)row * Dd;
        #pragma unroll
        for (int j = 0; j < 10; ++j) {
            int c4 = (tid & 15) + 16 * j;      // float4 slot 0..159
            int d = c4 * 4;
            int half = (j >= 5) ? 1 : 0;
            int cloc = c4 - half * 80;
            float4 fv = *(const float4*)(frow + d);
            float4 gv = *(const float4*)(grow + d);
            float h0 = fv.x + gv.x; h0 = h0 > 0.f ? h0 : 0.f;
            float h1 = fv.y + gv.y; h1 = h1 > 0.f ? h1 : 0.f;
            float h2 = fv.z + gv.z; h2 = h2 > 0.f ? h2 : 0.f;
            float h3 = fv.w + gv.w; h3 = h3 > 0.f ? h3 : 0.f;
            ushort4v pk;
            pk.x = f2bf(h0); pk.y = f2bf(h1); pk.z = f2bf(h2); pk.w = f2bf(h3);
            *(ushort4v*)(&u.hlds[half * 20992 + row * 328 + cloc * 4]) = pk;
        }
    }
    __syncthreads();

    // ---- K loop: 40 steps of 16, B double-buffered in regs, no barriers ----
    {
        const int arow = (rg * 32 + l31) * 328 + lh * 8;   // ushort offset base
        ushort8 Bbuf[2][4];
        #pragma unroll
        for (int ct = 0; ct < 4; ++ct)
            Bbuf[0][ct] = *(const ushort8*)(bbase + ct * 512);
        #pragma unroll
        for (int ks = 0; ks < 40; ++ks) {
            if (ks < 39) {
                #pragma unroll
                for (int ct = 0; ct < 4; ++ct)
                    Bbuf[(ks + 1) & 1][ct] =
                        *(const ushort8*)(bbase + (ks + 1) * 2048 + ct * 512);
            }
            const int bufo = (ks >= 20) ? 20992 : 0;
            const int kk = (ks >= 20) ? (ks - 20) : ks;
            ushort8 av = *(const ushort8*)(&u.hlds[bufo + arow + kk * 16]);
            bf16x8 afrag = __builtin_bit_cast(bf16x8, av);
            #pragma unroll
            for (int ct = 0; ct < 4; ++ct) {
                bf16x8 bfrag = __builtin_bit_cast(bf16x8, Bbuf[ks & 1][ct]);
                acc[ct] = __builtin_amdgcn_mfma_f32_32x32x16_bf16(afrag, bfrag, acc[ct], 0, 0, 0);
            }
        }
    }

    // ---- tail column: dot(h_row, wtail) from LDS ----
    #pragma unroll
    for (int j = 0; j < 10; ++j) {
        int c4 = ssub + 16 * j;                // 0..159
        int half = (c4 >= 80) ? 1 : 0;
        int cloc = c4 - half * 80;
        ushort4v hv = *(const ushort4v*)(&u.hlds[half * 20992 + srow * 328 + cloc * 4]);
        float4 wv = *(const float4*)(&wtld[c4 * 4]);
        tailAcc += bf2f(hv.x) * wv.x + bf2f(hv.y) * wv.y +
                   bf2f(hv.z) * wv.z + bf2f(hv.w) * wv.w;
    }
    tailAcc += __shfl_xor(tailAcc, 1);
    tailAcc += __shfl_xor(tailAcc, 2);
    tailAcc += __shfl_xor(tailAcc, 4);
    tailAcc += __shfl_xor(tailAcc, 8);
    if (ssub == 0) sTail[srow] = tailAcc + b_out[1024];

    // ---- + b_out ----
    #pragma unroll
    for (int ct = 0; ct < 4; ++ct) {
        float bo = b_out[cg * 128 + ct * 32 + l31];
        #pragma unroll
        for (int r = 0; r < 16; ++r) acc[ct][r] += bo;
    }

    // C/D layout: col = cg*128 + ct*32 + l31 ; rowloc = (r&3) + 8*(r>>2) + 4*lh (0..31)
    // absolute row = rg*32 + rowloc.

    // ---- row max (in-reg over ct, shfl over 32 cols, combine 8 cgs in LDS) ----
    {
        float m[16];
        #pragma unroll
        for (int r = 0; r < 16; ++r) {
            m[r] = fmaxf(fmaxf(acc[0][r], acc[1][r]), fmaxf(acc[2][r], acc[3][r]));
            #pragma unroll
            for (int msk = 1; msk < 32; msk <<= 1) m[r] = fmaxf(m[r], __shfl_xor(m[r], msk));
        }
        if (l31 == 0) {
            #pragma unroll
            for (int r = 0; r < 16; ++r) {
                int rowloc = (r & 3) + 8 * (r >> 2) + 4 * lh;
                sPart[cg * 64 + rg * 32 + rowloc] = m[r];
            }
        }
    }
    __syncthreads();
    if (tid < 64) {
        float m = sTail[tid];
        #pragma unroll
        for (int c = 0; c < 8; ++c) m = fmaxf(m, sPart[c * 64 + tid]);
        sRed[tid] = m;
    }
    __syncthreads();

    // ---- sum exp ----
    {
        float sv[16];
        #pragma unroll
        for (int r = 0; r < 16; ++r) {
            int rowloc = (r & 3) + 8 * (r >> 2) + 4 * lh;
            float mx = sRed[rg * 32 + rowloc];
            sv[r] = __expf(acc[0][r] - mx) + __expf(acc[1][r] - mx) +
                    __expf(acc[2][r] - mx) + __expf(acc[3][r] - mx);
            #pragma unroll
            for (int msk = 1; msk < 32; msk <<= 1) sv[r] += __shfl_xor(sv[r], msk);
        }
        if (l31 == 0) {
            #pragma unroll
            for (int r = 0; r < 16; ++r) {
                int rowloc = (r & 3) + 8 * (r >> 2) + 4 * lh;
                sPart[cg * 64 + rg * 32 + rowloc] = sv[r];
            }
        }
    }
    __syncthreads();
    if (tid < 64) {
        float mx = sRed[tid];
        float sv = __expf(sTail[tid] - mx);
        #pragma unroll
        for (int c = 0; c < 8; ++c) sv += sPart[c * 64 + tid];
        sRed[tid] = mx + logf(sv);  // lse
    }
    __syncthreads();   // sRed ready; hlds dead -> sOut aliasing OK

    // ---- write: 4 groups of 16 rows, LDS-staged, NT float4 drain ----
    #pragma unroll
    for (int grp = 0; grp < 4; ++grp) {
        if (rg == (grp >> 1)) {
            const int rb = (grp & 1) * 8;     // regs rb..rb+7 hold rows grp*16..+15
            #pragma unroll
            for (int rr = 0; rr < 8; ++rr) {
                int r = rb + rr;
                int row16 = (r & 3) + 8 * ((r >> 2) & 1) + 4 * lh;  // 0..15
                float lse = sRed[grp * 16 + row16];
                #pragma unroll
                for (int ct = 0; ct < 4; ++ct) {
                    u.sOut[row16 * 1025 + cg * 128 + ct * 32 + l31] = acc[ct][r] - lse;
                }
            }
        }
        if (tid < 16) u.sOut[tid * 1025 + 1024] = sTail[grp * 16 + tid] - sRed[grp * 16 + tid];
        __syncthreads();
        // 16*1025 = 16400 floats = 4100 float4
        float* outp = out + (rowbase + grp * 16) * (size_t)V1c;
        #pragma unroll
        for (int k = 0; k < 4; ++k) {
            int i4 = tid + 1024 * k;
            floatx4 v = *(const floatx4*)(&u.sOut[4 * i4]);
            __builtin_nontemporal_store(v, (floatx4*)(outp + 4 * i4));
        }
        if (tid < 4) {
            int i4 = tid + 4096;
            floatx4 v = *(const floatx4*)(&u.sOut[4 * i4]);
            __builtin_nontemporal_store(v, (floatx4*)(outp + 4 * i4));
        }
        __syncthreads();
    }
}

extern "C" void kernel_launch(void* const* d_in, const int* in_sizes, int n_in,
                              void* d_out, int out_size, void* d_ws, size_t ws_size,
                              hipStream_t stream) {
    const float* enc   = (const float*)d_in[0];
    const float* pred  = (const float*)d_in[1];
    const float* Wenc  = (const float*)d_in[2];
    const float* benc  = (const float*)d_in[3];
    const float* Wpred = (const float*)d_in[4];
    const float* bpred = (const float*)d_in[5];
    const float* Wout  = (const float*)d_in[6];
    const float* bout  = (const float*)d_in[7];

    float* f = (float*)d_ws;                                     // 655360 f32
    float* g = f + (size_t)Bb * Tt * Dd;                         // 327680 f32
    unsigned short* Wb3 = (unsigned short*)(g + (size_t)Bb * Uu * Dd);  // 655360 u16
    float* wtail = (float*)(Wb3 + 8 * 81920);                    // 640 f32

    prep<<<512, 640, 0, stream>>>(enc, Wenc, benc, f, pred, Wpred, bpred, g,
                                  Wout, Wb3, wtail);
    joint_main<<<Bb * Tt * 2, 1024, 0, stream>>>(f, g, Wb3, wtail, bout, (float*)d_out);
}

// Round 17
// 375.805 us; speedup vs baseline: 1.1296x; 1.0003x over previous
//
#include <hip/hip_runtime.h>
#include <hip/hip_bf16.h>

#define Bb 4
#define Tt 256
#define Uu 128
#define H1 512
#define H2 640
#define Dd 640
#define V1c 1025

typedef __bf16 bf16x8 __attribute__((ext_vector_type(8)));
typedef unsigned short ushort8 __attribute__((ext_vector_type(8)));
typedef unsigned short ushort4v __attribute__((ext_vector_type(4)));
typedef float floatx4 __attribute__((ext_vector_type(4)));
typedef float floatx16 __attribute__((ext_vector_type(16)));

static __device__ __forceinline__ unsigned short f2bf(float x) {
    union { float f; unsigned u; } a; a.f = x;
    unsigned r = a.u + 0x7fffu + ((a.u >> 16) & 1u);
    return (unsigned short)(r >> 16);
}
static __device__ __forceinline__ float bf2f(unsigned short x) {
    union { unsigned u; float f; } a; a.u = ((unsigned)x) << 16; return a.f;
}

// ---------------- prep: fg linears (blocks 0..191) + Wb3 swizzle (192..511) ----------------
// Wb3[cg][ks][ct][l31][lh][8] (ushort): 32x32x16 B-fragment order.
// offset = cg*81920 + ks*2048 + ct*512 + l31*16 + lh*8 + j
// source: v = cg*128 + ct*32 + l31 ; d = ks*16 + lh*8 + j   (ks 0..39)
__global__ __launch_bounds__(640) void prep(const float* __restrict__ enc,
                                            const float* __restrict__ Wenc,
                                            const float* __restrict__ benc,
                                            float* __restrict__ f,
                                            const float* __restrict__ pred,
                                            const float* __restrict__ Wpred,
                                            const float* __restrict__ bpred,
                                            float* __restrict__ g,
                                            const float* __restrict__ Wout,
                                            unsigned short* __restrict__ Wb3,
                                            float* __restrict__ wtail) {
    __shared__ __align__(16) float sh[640 * 8];
    const int tid = threadIdx.x;

    if (blockIdx.x < 192) {
        const bool isF = blockIdx.x < 128;
        const float* in   = isF ? enc : pred;
        const float* W    = isF ? Wenc : Wpred;
        const float* bias = isF ? benc : bpred;
        float* out        = isF ? f : g;
        const int H    = isF ? H1 : H2;
        const int Tdim = isF ? Tt : Uu;
        const int blk  = isF ? (int)blockIdx.x : (int)blockIdx.x - 128;
        const int tBlocks = Tdim >> 3;
        const int b  = blk / tBlocks;
        const int t0 = (blk % tBlocks) << 3;
        const float* inB = in + (size_t)b * H * Tdim + t0;

        for (int h = tid; h < H; h += 640) {
            float4 v0 = *(const float4*)(inB + (size_t)h * Tdim);
            float4 v1 = *(const float4*)(inB + (size_t)h * Tdim + 4);
            *(float4*)(&sh[h * 8])     = v0;
            *(float4*)(&sh[h * 8 + 4]) = v1;
        }
        __syncthreads();

        const int d = tid;
        float acc[8];
        #pragma unroll
        for (int j = 0; j < 8; ++j) acc[j] = 0.f;
        #pragma unroll 4
        for (int h = 0; h < H; ++h) {
            float w = W[(size_t)h * Dd + d];
            float4 s0 = *(const float4*)(&sh[h * 8]);
            float4 s1 = *(const float4*)(&sh[h * 8 + 4]);
            acc[0] += s0.x * w; acc[1] += s0.y * w; acc[2] += s0.z * w; acc[3] += s0.w * w;
            acc[4] += s1.x * w; acc[5] += s1.y * w; acc[6] += s1.z * w; acc[7] += s1.w * w;
        }
        float bv = bias[d];
        float* o = out + ((size_t)b * Tdim + t0) * Dd + d;
        #pragma unroll
        for (int j = 0; j < 8; ++j) o[(size_t)j * Dd] = acc[j] + bv;
    } else {
        // one block per (cg, ks): 16 d-rows x 128 v-cols
        float (*tile)[129] = (float(*)[129])sh;    // 16 x 129 (padded)
        const int blk2 = blockIdx.x - 192;         // 0..319
        const int cg = blk2 / 40;
        const int ks = blk2 % 40;

        if (tid < 512) {
            #pragma unroll
            for (int i = 0; i < 4; ++i) {
                int idx = tid + 512 * i;           // 0..2047
                int d_loc = idx >> 7;              // 0..15
                int v_loc = idx & 127;
                tile[d_loc][v_loc] = Wout[(size_t)(ks * 16 + d_loc) * V1c + cg * 128 + v_loc];
            }
        }
        __syncthreads();

        if (tid < 256) {
            int ct  = tid >> 6;
            int rem = tid & 63;
            int l31 = rem >> 1;
            int lh  = rem & 1;
            int v_loc = ct * 32 + l31;
            ushort8 pk;
            #pragma unroll
            for (int j = 0; j < 8; ++j) pk[j] = f2bf(tile[lh * 8 + j][v_loc]);
            *(ushort8*)(Wb3 + (size_t)cg * 81920 + ks * 2048 + tid * 8) = pk;
        }
        if (blk2 == 0 && tid < Dd) wtail[tid] = Wout[(size_t)tid * V1c + 1024];
    }
}

// ---------------- fused joint + log-softmax (32x32x16 MFMA, 16 waves) ----------------
// 2048 blocks x 1024 thr. Block: 64 rows x 1025 cols.
// Wave grid: 2 row-groups x 8 col-groups; wave tile 32x128 = 4 tiles of 32x32.
// acc = 4 x f32x16 = 64 AGPR -> ~115 regs/thread < 128 cap -> 4 waves/SIMD.
// B traffic unchanged vs R12 (1.31MB/block); B-loads contiguous 1KB (Wb3).
__global__ __launch_bounds__(1024) void joint_main(const float* __restrict__ f,
                                                   const float* __restrict__ g,
                                                   const unsigned short* __restrict__ Wb3,
                                                   const float* __restrict__ wtail,
                                                   const float* __restrict__ b_out,
                                                   float* __restrict__ out) {
    __shared__ __align__(16) union UU {
        unsigned short hlds[2 * 64 * 328];   // 83,968 B (two half-panels, stride 328)
        float sOut[16 * 1025];               // 65,600 B (aliases dead hlds)
    } u;
    __shared__ float wtld[640];
    __shared__ float sPart[8 * 64];
    __shared__ float sRed[64];
    __shared__ float sTail[64];

    const int tid = threadIdx.x;
    const int l = tid & 63;
    const int w = tid >> 6;       // wave 0..15
    const int rg = w >> 3;        // row group 0..1 (32 rows)
    const int cg = w & 7;         // col group 0..7 (128 cols)
    const int l31 = l & 31;
    const int lh = l >> 5;        // 0/1

    const int blk = blockIdx.x;
    const int uhalf = blk & 1;
    const int t = (blk >> 1) & 255;
    const int b = blk >> 9;
    const int u0 = uhalf * 64;
    const size_t fbase = ((size_t)b * Tt + t) * Dd;
    const size_t gbase = ((size_t)b * Uu + u0) * Dd;
    const size_t rowbase = (size_t)(b * Tt + t) * Uu + u0;

    if (tid < Dd) wtld[tid] = wtail[tid];

    floatx16 acc[4];
    #pragma unroll
    for (int ct = 0; ct < 4; ++ct)
        #pragma unroll
        for (int r = 0; r < 16; ++r) acc[ct][r] = 0.f;

    const unsigned short* __restrict__ bbase = Wb3 + (size_t)cg * 81920 + (l31 * 16 + lh * 8);
    float tailAcc = 0.f;
    const int srow = tid >> 4;    // 64 rows, 16 threads each
    const int ssub = tid & 15;

    // ---- stage FULL h = relu(f+g) panel: 64 rows x 640 cols bf16 ----
    {
        const int row = tid >> 4;
        const float* frow = f + fbase;
        const float* grow = g + gbase + (size_t)row * Dd;
        #pragma unroll
        for (int j = 0; j < 10; ++j) {
            int c4 = (tid & 15) + 16 * j;      // float4 slot 0..159
            int d = c4 * 4;
            int half = (j >= 5) ? 1 : 0;
            int cloc = c4 - half * 80;
            float4 fv = *(const float4*)(frow + d);
            float4 gv = *(const float4*)(grow + d);
            float h0 = fv.x + gv.x; h0 = h0 > 0.f ? h0 : 0.f;
            float h1 = fv.y + gv.y; h1 = h1 > 0.f ? h1 : 0.f;
            float h2 = fv.z + gv.z; h2 = h2 > 0.f ? h2 : 0.f;
            float h3 = fv.w + gv.w; h3 = h3 > 0.f ? h3 : 0.f;
            ushort4v pk;
            pk.x = f2bf(h0); pk.y = f2bf(h1); pk.z = f2bf(h2); pk.w = f2bf(h3);
            *(ushort4v*)(&u.hlds[half * 20992 + row * 328 + cloc * 4]) = pk;
        }
    }
    __syncthreads();

    // ---- K loop: 40 steps of 16, B double-buffered in regs, no barriers ----
    {
        const int arow = (rg * 32 + l31) * 328 + lh * 8;   // ushort offset base
        ushort8 Bbuf[2][4];
        #pragma unroll
        for (int ct = 0; ct < 4; ++ct)
            Bbuf[0][ct] = *(const ushort8*)(bbase + ct * 512);
        #pragma unroll
        for (int ks = 0; ks < 40; ++ks) {
            if (ks < 39) {
                #pragma unroll
                for (int ct = 0; ct < 4; ++ct)
                    Bbuf[(ks + 1) & 1][ct] =
                        *(const ushort8*)(bbase + (ks + 1) * 2048 + ct * 512);
            }
            const int bufo = (ks >= 20) ? 20992 : 0;
            const int kk = (ks >= 20) ? (ks - 20) : ks;
            ushort8 av = *(const ushort8*)(&u.hlds[bufo + arow + kk * 16]);
            bf16x8 afrag = __builtin_bit_cast(bf16x8, av);
            #pragma unroll
            for (int ct = 0; ct < 4; ++ct) {
                bf16x8 bfrag = __builtin_bit_cast(bf16x8, Bbuf[ks & 1][ct]);
                acc[ct] = __builtin_amdgcn_mfma_f32_32x32x16_bf16(afrag, bfrag, acc[ct], 0, 0, 0);
            }
        }
    }

    // ---- tail column: dot(h_row, wtail) from LDS ----
    #pragma unroll
    for (int j = 0; j < 10; ++j) {
        int c4 = ssub + 16 * j;                // 0..159
        int half = (c4 >= 80) ? 1 : 0;
        int cloc = c4 - half * 80;
        ushort4v hv = *(const ushort4v*)(&u.hlds[half * 20992 + srow * 328 + cloc * 4]);
        float4 wv = *(const float4*)(&wtld[c4 * 4]);
        tailAcc += bf2f(hv.x) * wv.x + bf2f(hv.y) * wv.y +
                   bf2f(hv.z) * wv.z + bf2f(hv.w) * wv.w;
    }
    tailAcc += __shfl_xor(tailAcc, 1);
    tailAcc += __shfl_xor(tailAcc, 2);
    tailAcc += __shfl_xor(tailAcc, 4);
    tailAcc += __shfl_xor(tailAcc, 8);
    if (ssub == 0) sTail[srow] = tailAcc + b_out[1024];

    // ---- + b_out ----
    #pragma unroll
    for (int ct = 0; ct < 4; ++ct) {
        float bo = b_out[cg * 128 + ct * 32 + l31];
        #pragma unroll
        for (int r = 0; r < 16; ++r) acc[ct][r] += bo;
    }

    // C/D layout: col = cg*128 + ct*32 + l31 ; rowloc = (r&3) + 8*(r>>2) + 4*lh (0..31)
    // absolute row = rg*32 + rowloc.

    // ---- row max (in-reg over ct, shfl over 32 cols, combine 8 cgs in LDS) ----
    {
        float m[16];
        #pragma unroll
        for (int r = 0; r < 16; ++r) {
            m[r] = fmaxf(fmaxf(acc[0][r], acc[1][r]), fmaxf(acc[2][r], acc[3][r]));
            #pragma unroll
            for (int msk = 1; msk < 32; msk <<= 1) m[r] = fmaxf(m[r], __shfl_xor(m[r], msk));
        }
        if (l31 == 0) {
            #pragma unroll
            for (int r = 0; r < 16; ++r) {
                int rowloc = (r & 3) + 8 * (r >> 2) + 4 * lh;
                sPart[cg * 64 + rg * 32 + rowloc] = m[r];
            }
        }
    }
    __syncthreads();
    if (tid < 64) {
        float m = sTail[tid];
        #pragma unroll
        for (int c = 0; c < 8; ++c) m = fmaxf(m, sPart[c * 64 + tid]);
        sRed[tid] = m;
    }
    __syncthreads();

    // ---- sum exp ----
    {
        float sv[16];
        #pragma unroll
        for (int r = 0; r < 16; ++r) {
            int rowloc = (r & 3) + 8 * (r >> 2) + 4 * lh;
            float mx = sRed[rg * 32 + rowloc];
            sv[r] = __expf(acc[0][r] - mx) + __expf(acc[1][r] - mx) +
                    __expf(acc[2][r] - mx) + __expf(acc[3][r] - mx);
            #pragma unroll
            for (int msk = 1; msk < 32; msk <<= 1) sv[r] += __shfl_xor(sv[r], msk);
        }
        if (l31 == 0) {
            #pragma unroll
            for (int r = 0; r < 16; ++r) {
                int rowloc = (r & 3) + 8 * (r >> 2) + 4 * lh;
                sPart[cg * 64 + rg * 32 + rowloc] = sv[r];
            }
        }
    }
    __syncthreads();
    if (tid < 64) {
        float mx = sRed[tid];
        float sv = __expf(sTail[tid] - mx);
        #pragma unroll
        for (int c = 0; c < 8; ++c) sv += sPart[c * 64 + tid];
        sRed[tid] = mx + logf(sv);  // lse
    }
    __syncthreads();   // sRed ready; hlds dead -> sOut aliasing OK

    // ---- write: 4 groups of 16 rows, LDS-staged, NT float4 drain ----
    #pragma unroll
    for (int grp = 0; grp < 4; ++grp) {
        if (rg == (grp >> 1)) {
            const int rb = (grp & 1) * 8;     // regs rb..rb+7 hold rows grp*16..+15
            #pragma unroll
            for (int rr = 0; rr < 8; ++rr) {
                int r = rb + rr;
                int row16 = (r & 3) + 8 * ((r >> 2) & 1) + 4 * lh;  // 0..15
                float lse = sRed[grp * 16 + row16];
                #pragma unroll
                for (int ct = 0; ct < 4; ++ct) {
                    u.sOut[row16 * 1025 + cg * 128 + ct * 32 + l31] = acc[ct][r] - lse;
                }
            }
        }
        if (tid < 16) u.sOut[tid * 1025 + 1024] = sTail[grp * 16 + tid] - sRed[grp * 16 + tid];
        __syncthreads();
        // 16*1025 = 16400 floats = 4100 float4
        float* outp = out + (rowbase + grp * 16) * (size_t)V1c;
        #pragma unroll
        for (int k = 0; k < 4; ++k) {
            int i4 = tid + 1024 * k;
            floatx4 v = *(const floatx4*)(&u.sOut[4 * i4]);
            __builtin_nontemporal_store(v, (floatx4*)(outp + 4 * i4));
        }
        if (tid < 4) {
            int i4 = tid + 4096;
            floatx4 v = *(const floatx4*)(&u.sOut[4 * i4]);
            __builtin_nontemporal_store(v, (floatx4*)(outp + 4 * i4));
        }
        __syncthreads();
    }
}

extern "C" void kernel_launch(void* const* d_in, const int* in_sizes, int n_in,
                              void* d_out, int out_size, void* d_ws, size_t ws_size,
                              hipStream_t stream) {
    const float* enc   = (const float*)d_in[0];
    const float* pred  = (const float*)d_in[1];
    const float* Wenc  = (const float*)d_in[2];
    const float* benc  = (const float*)d_in[3];
    const float* Wpred = (const float*)d_in[4];
    const float* bpred = (const float*)d_in[5];
    const float* Wout  = (const float*)d_in[6];
    const float* bout  = (const float*)d_in[7];

    float* f = (float*)d_ws;                                     // 655360 f32
    float* g = f + (size_t)Bb * Tt * Dd;                         // 327680 f32
    unsigned short* Wb3 = (unsigned short*)(g + (size_t)Bb * Uu * Dd);  // 655360 u16
    float* wtail = (float*)(Wb3 + 8 * 81920);                    // 640 f32

    prep<<<512, 640, 0, stream>>>(enc, Wenc, benc, f, pred, Wpred, bpred, g,
                                  Wout, Wb3, wtail);
    joint_main<<<Bb * Tt * 2, 1024, 0, stream>>>(f, g, Wb3, wtail, bout, (float*)d_out);
}